// Round 9
// baseline (30.373 us; speedup 1.0000x reference)
//
#include <hip/hip_runtime.h>
#include <hip/hip_bf16.h>
#include <cstdint>
#include <cstddef>

// Problem constants (from reference)
#define NN     50000   // nodes
#define FIN    128
#define FOUT   128
#define FLIN   64
#define BM     32      // rows per tile
#define NT     1563    // ceil(NN/BM)
#define TPB    4       // tiles per block
#define GRID   391     // 391*4 = 1564 >= NT, near-perfect balance

typedef __attribute__((ext_vector_type(4))) float f32x4;
typedef __attribute__((ext_vector_type(8))) short s16x8;

// Saturating-limit fast sigmoid/tanh: NaN-free at +/-inf.
__device__ __forceinline__ float fsigmoid(float x) {
    return __builtin_amdgcn_rcpf(1.f + __builtin_amdgcn_exp2f(-1.4426950408889634f * x));
}
__device__ __forceinline__ float ftanh(float x) {
    return 1.f - 2.f * __builtin_amdgcn_rcpf(1.f + __builtin_amdgcn_exp2f(2.8853900817779268f * x));
}

// Pack 8 floats -> bf16 fragment via v_cvt_pk_bf16_f32 (RNE).
__device__ __forceinline__ s16x8 pack_frag8(f32x4 a, f32x4 b) {
    union { unsigned int u[4]; s16x8 v; } r;
    __hip_bfloat162 p0 = __float22bfloat162_rn(make_float2(a.x, a.y));
    __hip_bfloat162 p1 = __float22bfloat162_rn(make_float2(a.z, a.w));
    __hip_bfloat162 p2 = __float22bfloat162_rn(make_float2(b.x, b.y));
    __hip_bfloat162 p3 = __float22bfloat162_rn(make_float2(b.z, b.w));
    r.u[0] = *(unsigned int*)&p0;
    r.u[1] = *(unsigned int*)&p1;
    r.u[2] = *(unsigned int*)&p2;
    r.u[3] = *(unsigned int*)&p3;
    return r.v;
}

// Gather one B fragment (16x16x32 bf16) from row-major (K x ncols) f32:
// lane holds W[kb*32 + lg*8 + i][ct*16 + lc], i = 0..7.
__device__ __forceinline__ s16x8 gather_bfrag(const float* __restrict__ W,
                                              int ncols, int kb, int ct,
                                              int lg, int lc) {
    const float* p = W + (size_t)(kb * 32 + lg * 8) * ncols + ct * 16 + lc;
    float f[8];
    #pragma unroll
    for (int i = 0; i < 8; ++i) f[i] = p[(size_t)i * ncols];
    f32x4 a = {f[0], f[1], f[2], f[3]};
    f32x4 b = {f[4], f[5], f[6], f[7]};
    return pack_frag8(a, b);
}

// ---------------------------------------------------------------------------
// v9: 391 blocks x 512 threads (8 waves; wave w = gate col-tile w).
// Prologue: load ALL (<=4) x tiles to regs (coalesced dwordx4), convert ONCE
// to bf16, ds_write into 4 swizzled LDS buffers; gate+lin B-frags -> 64 VGPR
// (weight-gather latency hides the x loads). One barrier. Steady state: pure
// LDS + MFMA + epilogue, zero global staging, one lgkmcnt barrier per tile.
// ---------------------------------------------------------------------------
__global__ __launch_bounds__(512, 2) void gclstm_fused(
    const float* __restrict__ x,
    const float* __restrict__ Wx,               // (4,128,128)
    const float* __restrict__ b_gate,           // (4,1,128)
    const float* __restrict__ w_c,              // (3,1,128)
    const float* __restrict__ cheb_b,           // (4,128)
    const float* __restrict__ lin_W,            // (128,64)
    const float* __restrict__ lin_b,            // (64)
    float* __restrict__ out)                    // (NN,64)
{
    __shared__ __align__(16) unsigned char ldsx[TPB][BM * 256];  // 4 x 8KB bf16 x-tiles
    __shared__ __align__(16) unsigned char ldsh[2][BM * 256];    // 2 x 8KB bf16 h

    const int tid  = threadIdx.x;
    const int w    = tid >> 6;       // wave 0..7 = phase-1 col tile
    const int lane = tid & 63;
    const int lg   = lane >> 4;
    const int lc   = lane & 15;
    const int b    = blockIdx.x;
    const int t0   = b * TPB;
    const int cnt  = (NT - t0 < TPB) ? (NT - t0) : TPB;   // 4, last block 3

    // ---- prologue 1: issue ALL x loads (coalesced dwordx4) ----
    const int srow = tid >> 4;            // staging row 0..31
    const int scol = (tid & 15) * 8;      // staging col 0..120
    f32x4 xv[TPB][2];
    #pragma unroll
    for (int jt = 0; jt < TPB; ++jt) {
        if (jt < cnt) {
            long grow = (long)(t0 + jt) * BM + srow;
            if (grow > NN - 1) grow = NN - 1;      // pad rows masked at store
            const float* rp = x + grow * FIN + scol;
            xv[jt][0] = *(const f32x4*)(rp);
            xv[jt][1] = *(const f32x4*)(rp + 4);
        }
    }

    // ---- prologue 2: weights -> registers (hides x-load latency) ----
    s16x8 bfr[3][4];    // gates i = Wx[0], c = Wx[2], o = Wx[3]; ct = w
    #pragma unroll
    for (int kb = 0; kb < 4; ++kb) {
        bfr[0][kb] = gather_bfrag(Wx + 0 * (FIN * FOUT), FOUT, kb, w, lg, lc);
        bfr[1][kb] = gather_bfrag(Wx + 2 * (FIN * FOUT), FOUT, kb, w, lg, lc);
        bfr[2][kb] = gather_bfrag(Wx + 3 * (FIN * FOUT), FOUT, kb, w, lg, lc);
    }
    const int rt2  = w & 1;               // phase-2 row tile
    const int ctL  = w >> 1;              // phase-2 col tile
    const int colL = ctL * 16 + lc;
    s16x8 lfr[4];
    #pragma unroll
    for (int kb = 0; kb < 4; ++kb)
        lfr[kb] = gather_bfrag(lin_W, FLIN, kb, ctL, lg, lc);

    // ---- prologue 3: convert once, write bf16 x tiles (swizzled) ----
    {
        const int byte = (srow * 256 + scol * 2) ^ ((srow & 7) << 4);
        #pragma unroll
        for (int jt = 0; jt < TPB; ++jt)
            if (jt < cnt)
                *(s16x8*)(ldsx[jt] + byte) = pack_frag8(xv[jt][0], xv[jt][1]);
    }

    // ---- biases ----
    const int col1 = w * 16 + lc;
    const float bi  = cheb_b[0 * 128 + col1] + b_gate[0 * 128 + col1];
    const float bc  = cheb_b[2 * 128 + col1] + b_gate[2 * 128 + col1];
    const float bo  = cheb_b[3 * 128 + col1] + b_gate[3 * 128 + col1];
    const float wco = w_c[2 * 128 + col1];
    const float lb  = lin_b[colL];

    __syncthreads();   // x tiles visible; no globals needed past this point

    for (int j = 0; j < cnt; ++j) {
        const unsigned char* xb = ldsx[j];
        const long m0 = (long)(t0 + j) * BM;

        // ---- phase 1: A-frags from bf16 LDS (no cvt), B from registers ----
        f32x4 acc[2][3];
        #pragma unroll
        for (int rt = 0; rt < 2; ++rt)
            #pragma unroll
            for (int gg = 0; gg < 3; ++gg)
                acc[rt][gg] = (f32x4){0.f, 0.f, 0.f, 0.f};

        #pragma unroll
        for (int rt = 0; rt < 2; ++rt) {
            const int row = rt * 16 + lc;
            const int sw  = (row & 7) << 4;
            const unsigned char* rbase = xb + row * 256;
            #pragma unroll
            for (int kb = 0; kb < 4; ++kb) {
                s16x8 afr = *(const s16x8*)(rbase + ((kb * 64 + lg * 16) ^ sw));
                acc[rt][0] = __builtin_amdgcn_mfma_f32_16x16x32_bf16(afr, bfr[0][kb], acc[rt][0], 0, 0, 0);
                acc[rt][1] = __builtin_amdgcn_mfma_f32_16x16x32_bf16(afr, bfr[1][kb], acc[rt][1], 0, 0, 0);
                acc[rt][2] = __builtin_amdgcn_mfma_f32_16x16x32_bf16(afr, bfr[2][kb], acc[rt][2], 0, 0, 0);
            }
        }

        // ---- epilogue: LSTM cell (H=C=0), h -> ldsh[j&1] ----
        #pragma unroll
        for (int rt = 0; rt < 2; ++rt)
            #pragma unroll
            for (int r = 0; r < 4; ++r) {
                float I = fsigmoid(acc[rt][0][r] + bi);
                float T = ftanh(acc[rt][1][r] + bc);
                float C = I * T;
                float O = fsigmoid(acc[rt][2][r] + wco * C + bo);
                float h = fmaxf(O * ftanh(C), 0.f);
                int row  = rt * 16 + lg * 4 + r;
                int byte = (row * 256 + col1 * 2) ^ ((row & 7) << 4);
                *(unsigned short*)(ldsh[j & 1] + byte) = __bfloat16_as_ushort(__float2bfloat16(h));
            }

        // h visible to all waves; out-stores from prior tiles stay in flight
        asm volatile("s_waitcnt lgkmcnt(0)\n\ts_barrier" ::: "memory");

        // ---- phase 2: out = h @ lin_W + lin_b (lin frags in registers) ----
        f32x4 acc2 = {0.f, 0.f, 0.f, 0.f};
        #pragma unroll
        for (int kb = 0; kb < 4; ++kb) {
            int row  = rt2 * 16 + lc;
            int byte = (row * 256 + kb * 64 + lg * 16) ^ ((row & 7) << 4);
            s16x8 ha = *(const s16x8*)(ldsh[j & 1] + byte);
            acc2 = __builtin_amdgcn_mfma_f32_16x16x32_bf16(ha, lfr[kb], acc2, 0, 0, 0);
        }
        #pragma unroll
        for (int r = 0; r < 4; ++r) {
            long row = m0 + rt2 * 16 + lg * 4 + r;
            if (row < NN) out[row * FLIN + colL] = acc2[r] + lb;
        }
    }
}

extern "C" void kernel_launch(void* const* d_in, const int* in_sizes, int n_in,
                              void* d_out, int out_size, void* d_ws, size_t ws_size,
                              hipStream_t stream) {
    const float* x      = (const float*)d_in[0];
    // d_in[1] edge_index, d_in[2] edge_weight, d_in[6] cheb_W: dead (H=C=0)
    const float* Wx     = (const float*)d_in[3];
    const float* b_gate = (const float*)d_in[4];
    const float* w_c    = (const float*)d_in[5];
    const float* cheb_b = (const float*)d_in[7];
    const float* lin_W  = (const float*)d_in[8];
    const float* lin_b  = (const float*)d_in[9];
    float* out          = (float*)d_out;

    gclstm_fused<<<GRID, 512, 0, stream>>>(x, Wx, b_gate, w_c, cheb_b, lin_W, lin_b, out);
}

// Round 10
// 26.980 us; speedup vs baseline: 1.1258x; 1.1258x over previous
//
#include <hip/hip_runtime.h>
#include <hip/hip_bf16.h>
#include <cstdint>
#include <cstddef>

// Problem constants (from reference)
#define NN     50000   // nodes
#define FIN    128
#define FOUT   128
#define FLIN   64
#define BM     32      // rows per tile
#define NT     1563    // ceil(NN/BM)
#define GRID   512     // 2 blocks/CU; blocks 0..26 own 4 tiles, rest 3

typedef __attribute__((ext_vector_type(4))) float f32x4;
typedef __attribute__((ext_vector_type(8))) short s16x8;

// Saturating-limit fast sigmoid/tanh: NaN-free at +/-inf.
__device__ __forceinline__ float fsigmoid(float x) {
    return __builtin_amdgcn_rcpf(1.f + __builtin_amdgcn_exp2f(-1.4426950408889634f * x));
}
__device__ __forceinline__ float ftanh(float x) {
    return 1.f - 2.f * __builtin_amdgcn_rcpf(1.f + __builtin_amdgcn_exp2f(2.8853900817779268f * x));
}

// Pack 8 floats -> bf16 fragment via v_cvt_pk_bf16_f32 (RNE).
__device__ __forceinline__ s16x8 pack_frag8(f32x4 a, f32x4 b) {
    union { unsigned int u[4]; s16x8 v; } r;
    __hip_bfloat162 p0 = __float22bfloat162_rn(make_float2(a.x, a.y));
    __hip_bfloat162 p1 = __float22bfloat162_rn(make_float2(a.z, a.w));
    __hip_bfloat162 p2 = __float22bfloat162_rn(make_float2(b.x, b.y));
    __hip_bfloat162 p3 = __float22bfloat162_rn(make_float2(b.z, b.w));
    r.u[0] = *(unsigned int*)&p0;
    r.u[1] = *(unsigned int*)&p1;
    r.u[2] = *(unsigned int*)&p2;
    r.u[3] = *(unsigned int*)&p3;
    return r.v;
}

// Gather one B fragment (16x16x32 bf16) from row-major (K x ncols) f32:
// lane holds W[kb*32 + lg*8 + i][ct*16 + lc], i = 0..7.
__device__ __forceinline__ s16x8 gather_bfrag(const float* __restrict__ W,
                                              int ncols, int kb, int ct,
                                              int lg, int lc) {
    const float* p = W + (size_t)(kb * 32 + lg * 8) * ncols + ct * 16 + lc;
    float f[8];
    #pragma unroll
    for (int i = 0; i < 8; ++i) f[i] = p[(size_t)i * ncols];
    f32x4 a = {f[0], f[1], f[2], f[3]};
    f32x4 b = {f[4], f[5], f[6], f[7]};
    return pack_frag8(a, b);
}

// Async-stage one 32x128 f32 x-tile into a 16KB LDS buffer via
// global_load_lds (wave-uniform linear dest + lane*16). LDS holds the
// XOR-swizzled row-major image: lds[row*512 + d] = x[row][(d ^ ((row&7)<<4))]
// achieved by pre-swizzling the per-lane GLOBAL source address (rule #21).
// Rows past NN are clamped to row NN-1 (garbage rows masked at store time).
// Per wave: 2 global_load_lds ops (vmcnt += 2).
__device__ __forceinline__ void stage_tile(unsigned char* ldsbuf,
                                           const float* __restrict__ x,
                                           int t, int w, int lane) {
    const long m0 = (long)t * BM;
    #pragma unroll
    for (int p = 0; p < 2; ++p) {
        int G   = p * 512 + w * 64 + lane;          // 16B-granule index 0..1023
        int row = G >> 5;                           // 32 granules per 512B row
        int inb = ((G & 31) * 16) ^ ((row & 7) << 4);
        long grow = m0 + row;
        if (grow > NN - 1) grow = NN - 1;
        const float* src = x + grow * FIN + (inb >> 2);
        unsigned char* dst = ldsbuf + (size_t)(p * 512 + w * 64) * 16; // wave-uniform
        __builtin_amdgcn_global_load_lds(
            (const __attribute__((address_space(1))) unsigned int*)src,
            (__attribute__((address_space(3))) unsigned int*)dst,
            16, 0, 0);
    }
}

// ---------------------------------------------------------------------------
// Pipelined persistent kernel v10 (= v7 with the VGPR cap fixed): 512 blocks
// x 512 threads (8 waves, wave w owns gate col-tile w). Gate i,c,o B-frags in
// registers (48 VGPR — launch_bounds(512,2) caps at 128, no spill; LDS already
// limits to 2 blocks/CU). lin_W frags in LDS (16KB). Two x buffers, rolling
// restage of tile j+2 after barrier j; one counted-vmcnt barrier per tile
// (stages drained, out-stores left in flight).
// ---------------------------------------------------------------------------
__global__ __launch_bounds__(512, 2) void gclstm_fused(
    const float* __restrict__ x,
    const float* __restrict__ Wx,               // (4,128,128)
    const float* __restrict__ b_gate,           // (4,1,128)
    const float* __restrict__ w_c,              // (3,1,128)
    const float* __restrict__ cheb_b,           // (4,128)
    const float* __restrict__ lin_W,            // (128,64)
    const float* __restrict__ lin_b,            // (64)
    float* __restrict__ out)                    // (NN,64)
{
    __shared__ __align__(16) unsigned char ldsx[2][BM * 512];   // 2 x 16KB f32 x-tiles
    __shared__ __align__(16) unsigned char ldsh[2][BM * 256];   // 2 x 8KB bf16 h
    __shared__ __align__(16) unsigned char ldsw[16 * 1024];     // 16KB lin frags

    const int tid  = threadIdx.x;
    const int w    = tid >> 6;       // wave 0..7 = phase-1 col tile
    const int lane = tid & 63;
    const int lg   = lane >> 4;
    const int lc   = lane & 15;
    const int b    = blockIdx.x;
    const int t0   = b * 3 + (b < 27 ? b : 27);
    const int cnt  = (b < 27) ? 4 : 3;

    // ---- burst: stage tiles 0,1 (async, no VGPR round-trip) ----
    stage_tile(ldsx[0], x, t0 + 0, w, lane);
    stage_tile(ldsx[1], x, t0 + 1, w, lane);

    // ---- gate weights -> registers (48 VGPR); latency overlaps the burst ----
    s16x8 bfr[3][4];    // gates i = Wx[0], c = Wx[2], o = Wx[3]; ct = w
    #pragma unroll
    for (int kb = 0; kb < 4; ++kb) {
        bfr[0][kb] = gather_bfrag(Wx + 0 * (FIN * FOUT), FOUT, kb, w, lg, lc);
        bfr[1][kb] = gather_bfrag(Wx + 2 * (FIN * FOUT), FOUT, kb, w, lg, lc);
        bfr[2][kb] = gather_bfrag(Wx + 3 * (FIN * FOUT), FOUT, kb, w, lg, lc);
    }

    // ---- lin_W fragments -> LDS (16 frags; wave w writes fi = 2w, 2w+1) ----
    #pragma unroll
    for (int it = 0; it < 2; ++it) {
        int fi = w * 2 + it;          // fi = ct*4 + kb
        s16x8 f = gather_bfrag(lin_W, FLIN, fi & 3, fi >> 2, lg, lc);
        *(s16x8*)(ldsw + ((size_t)fi * 64 + lane) * 16) = f;
    }

    // ---- biases ----
    const int col1 = w * 16 + lc;
    const float bi  = cheb_b[0 * 128 + col1] + b_gate[0 * 128 + col1];
    const float bc  = cheb_b[2 * 128 + col1] + b_gate[2 * 128 + col1];
    const float bo  = cheb_b[3 * 128 + col1] + b_gate[3 * 128 + col1];
    const float wco = w_c[2 * 128 + col1];
    const int rt2  = w & 1;                     // phase-2 row tile
    const int ctL  = w >> 1;                    // phase-2 col tile
    const int colL = ctL * 16 + lc;
    const float lb = lin_b[colL];

    __syncthreads();   // full drain once: tiles 0,1 + lin LDS writes visible

    for (int j = 0; j < cnt; ++j) {
        const unsigned char* xb = ldsx[j & 1];
        const long m0 = (long)(t0 + j) * BM;

        // ---- phase 1: A-frags from swizzled LDS f32, B from registers ----
        f32x4 acc[2][3];
        #pragma unroll
        for (int rt = 0; rt < 2; ++rt)
            #pragma unroll
            for (int gg = 0; gg < 3; ++gg)
                acc[rt][gg] = (f32x4){0.f, 0.f, 0.f, 0.f};

        #pragma unroll
        for (int rt = 0; rt < 2; ++rt) {
            const int row = rt * 16 + lc;
            const int sw  = (row & 7) << 4;
            const unsigned char* rbase = xb + row * 512;
            #pragma unroll
            for (int kb = 0; kb < 4; ++kb) {
                const int off = kb * 128 + lg * 32;
                f32x4 lo = *(const f32x4*)(rbase + (off ^ sw));
                f32x4 hi = *(const f32x4*)(rbase + ((off + 16) ^ sw));
                s16x8 afr = pack_frag8(lo, hi);
                acc[rt][0] = __builtin_amdgcn_mfma_f32_16x16x32_bf16(afr, bfr[0][kb], acc[rt][0], 0, 0, 0);
                acc[rt][1] = __builtin_amdgcn_mfma_f32_16x16x32_bf16(afr, bfr[1][kb], acc[rt][1], 0, 0, 0);
                acc[rt][2] = __builtin_amdgcn_mfma_f32_16x16x32_bf16(afr, bfr[2][kb], acc[rt][2], 0, 0, 0);
            }
        }

        // ---- epilogue: LSTM cell (H=C=0), h -> ldsh[j&1] ----
        #pragma unroll
        for (int rt = 0; rt < 2; ++rt)
            #pragma unroll
            for (int r = 0; r < 4; ++r) {
                float I = fsigmoid(acc[rt][0][r] + bi);
                float T = ftanh(acc[rt][1][r] + bc);
                float C = I * T;
                float O = fsigmoid(acc[rt][2][r] + wco * C + bo);
                float h = fmaxf(O * ftanh(C), 0.f);
                int row  = rt * 16 + lg * 4 + r;
                int byte = (row * 256 + col1 * 2) ^ ((row & 7) << 4);
                *(unsigned short*)(ldsh[j & 1] + byte) = __bfloat16_as_ushort(__float2bfloat16(h));
            }

        // ---- counted-vmcnt barrier (T4): drains the 2 stage ops issued last
        // iteration (older), leaves <=4 newest (out-stores) in flight; makes
        // h + x-stage visible to all waves. ----
        asm volatile("s_waitcnt vmcnt(4) lgkmcnt(0)\n\ts_barrier" ::: "memory");

        // ---- rolling restage: tile j+2 into the buffer just consumed ----
        if (j + 2 < cnt) stage_tile(ldsx[j & 1], x, t0 + j + 2, w, lane);

        // ---- phase 2: out = h @ lin_W + lin_b (lin frags from LDS) ----
        f32x4 acc2 = {0.f, 0.f, 0.f, 0.f};
        #pragma unroll
        for (int kb = 0; kb < 4; ++kb) {
            int row  = rt2 * 16 + lc;
            int byte = (row * 256 + kb * 64 + lg * 16) ^ ((row & 7) << 4);
            s16x8 ha = *(const s16x8*)(ldsh[j & 1] + byte);
            s16x8 lf = *(const s16x8*)(ldsw + ((size_t)(ctL * 4 + kb) * 64 + lane) * 16);
            acc2 = __builtin_amdgcn_mfma_f32_16x16x32_bf16(ha, lf, acc2, 0, 0, 0);
        }
        #pragma unroll
        for (int r = 0; r < 4; ++r) {
            long row = m0 + rt2 * 16 + lg * 4 + r;
            if (row < NN) out[row * FLIN + colL] = acc2[r] + lb;
        }
    }
}

extern "C" void kernel_launch(void* const* d_in, const int* in_sizes, int n_in,
                              void* d_out, int out_size, void* d_ws, size_t ws_size,
                              hipStream_t stream) {
    const float* x      = (const float*)d_in[0];
    // d_in[1] edge_index, d_in[2] edge_weight, d_in[6] cheb_W: dead (H=C=0)
    const float* Wx     = (const float*)d_in[3];
    const float* b_gate = (const float*)d_in[4];
    const float* w_c    = (const float*)d_in[5];
    const float* cheb_b = (const float*)d_in[7];
    const float* lin_W  = (const float*)d_in[8];
    const float* lin_b  = (const float*)d_in[9];
    float* out          = (float*)d_out;

    gclstm_fused<<<GRID, 512, 0, stream>>>(x, Wx, b_gate, w_c, cheb_b, lin_W, lin_b, out);
}